// Round 11
// baseline (426.513 us; speedup 1.0000x reference)
//
#include <hip/hip_runtime.h>
#include <hip/hip_bf16.h>

#define N_NODES 50000
#define N_EDGES 800000
#define NBK 196          // buckets of 256 dst nodes (dst>>8); 196*256 = 50176
#define BCAP 40          // per-bucket LDS stage capacity in k_bin (lambda=21, 4sigma)

typedef __attribute__((ext_vector_type(8))) short bf16x8;   // MFMA A/B frag
typedef __attribute__((ext_vector_type(4))) float f32x4;    // MFMA C/D frag

__device__ __forceinline__ float leaky(float l) { return (l >= 0.0f) ? l : 0.2f * l; }
__device__ __forceinline__ float blo(unsigned u) { return __uint_as_float(u << 16); }
__device__ __forceinline__ float bhi(unsigned u) { return __uint_as_float(u & 0xffff0000u); }
__device__ __forceinline__ unsigned short f2bu(float f) {
    __hip_bfloat16 hb = __float2bfloat16(f);   // RNE
    return *(unsigned short*)&hb;
}
__device__ __forceinline__ unsigned pk2(float a, float b) {
    return (unsigned)f2bu(a) | ((unsigned)f2bu(b) << 16);
}

// ---------------- k_hist196: per-bucket edge counts (LDS pre-aggregated) --------
__global__ void k_hist196(const int* __restrict__ ei, int* __restrict__ gcnt) {
    __shared__ int cnt[NBK];
    int tid = threadIdx.x;
    for (int i = tid; i < NBK; i += 256) cnt[i] = 0;
    __syncthreads();
    int e0 = blockIdx.x * 4096;
#pragma unroll
    for (int k = 0; k < 4; ++k) {
        int e = e0 + k * 1024 + tid * 4;
        if (e < N_EDGES) {
            int4 dv = *(const int4*)(ei + N_EDGES + e);
            atomicAdd(&cnt[dv.x >> 8], 1);
            atomicAdd(&cnt[dv.y >> 8], 1);
            atomicAdd(&cnt[dv.z >> 8], 1);
            atomicAdd(&cnt[dv.w >> 8], 1);
        }
    }
    __syncthreads();
    for (int b = tid; b < NBK; b += 256)
        if (cnt[b]) atomicAdd(&gcnt[b], cnt[b]);
}

// ---------------- k_scan196: 1-block exclusive scan -> bucket offsets -----------
__global__ void k_scan196(const int* __restrict__ gcnt, int* __restrict__ goff,
                          int* __restrict__ gcur) {
    __shared__ int wsum[4];
    int tid = threadIdx.x, lane = tid & 63, wid = tid >> 6;
    int v = (tid < NBK) ? gcnt[tid] : 0;
    int inc = v;
#pragma unroll
    for (int s = 1; s < 64; s <<= 1) {
        int t = __shfl_up(inc, s);
        if (lane >= s) inc += t;
    }
    if (lane == 63) wsum[wid] = inc;
    __syncthreads();
    if (tid == 0) {
        int s = 0;
#pragma unroll
        for (int w = 0; w < 4; ++w) { int t = wsum[w]; wsum[w] = s; s += t; }
    }
    __syncthreads();
    if (tid < NBK) {
        goff[tid] = wsum[wid] + inc - v;
        gcur[tid] = 0;
    }
}

// ---------------- k_bin: LDS-staged bucket routing (dense writes) ---------------
// R10 lesson: random 4B scatter = 64B/line at HBM (53MB for 3.2MB payload).
// Here records are staged per-bucket in LDS and flushed as ~84B contiguous
// chunks via global cursors -> write traffic ~8MB. Record = src | (dst&255)<<16
// (src < 50000 < 2^16). Slot order within a bucket is irrelevant downstream.
__global__ void __launch_bounds__(256)
k_bin(const int* __restrict__ ei, const int* __restrict__ goff,
      int* __restrict__ gcur, int* __restrict__ recs) {
    __shared__ int cnt[NBK];
    __shared__ int stage[NBK][BCAP];
    int tid = threadIdx.x;
    for (int i = tid; i < NBK; i += 256) cnt[i] = 0;
    __syncthreads();
    int e0 = blockIdx.x * 4096;
#pragma unroll
    for (int k = 0; k < 4; ++k) {
        int e = e0 + k * 1024 + tid * 4;
        if (e < N_EDGES) {
            int4 sv = *(const int4*)(ei + e);
            int4 dv = *(const int4*)(ei + N_EDGES + e);
            int ss[4] = {sv.x, sv.y, sv.z, sv.w};
            int dd[4] = {dv.x, dv.y, dv.z, dv.w};
#pragma unroll
            for (int j = 0; j < 4; ++j) {
                int b = dd[j] >> 8;
                int rec = ss[j] | ((dd[j] & 255) << 16);
                int p = atomicAdd(&cnt[b], 1);
                if (p < BCAP) stage[b][p] = rec;
                else {                         // rare overflow: direct store
                    int g = atomicAdd(&gcur[b], 1);
                    recs[goff[b] + g] = rec;
                }
            }
        }
    }
    __syncthreads();
    for (int b = tid; b < NBK; b += 256) {
        int nb = min(cnt[b], BCAP);
        if (nb > 0) {
            int g = atomicAdd(&gcur[b], nb);
            int d0 = goff[b] + g;
            for (int i = 0; i < nb; ++i) recs[d0 + i] = stage[b][i];
        }
    }
}

// ---------------- k1: MFMA GEMM + fp32 scores, ALL outputs coalesced (R10) ------
__global__ void __launch_bounds__(256, 4)
k1_mfma(const float* __restrict__ x, const float* __restrict__ state,
        const float* __restrict__ W, const float* __restrict__ a_src,
        const float* __restrict__ a_dst,
        unsigned short* __restrict__ hf2, float* __restrict__ s_src4,
        float* __restrict__ s_dst4) {
    __shared__ unsigned short alds[64 * 136];  // A tile bf16; reused as f32 h [64][68]
    __shared__ unsigned short wlds[64 * 136];  // W tile bf16
    int tid = threadIdx.x;
    int nb = blockIdx.x * 64;

    const float4* x4  = (const float4*)x;
    const float4* st4 = (const float4*)state;
    const float4* W4  = (const float4*)W;
    for (int idx = tid; idx < 2048; idx += 256) {
        int row = idx >> 5, qc = idx & 31;
        int n = nb + row;
        float4 v = make_float4(0.f, 0.f, 0.f, 0.f);
        if (n < N_NODES)
            v = (qc < 16) ? x4[(long)n * 16 + qc] : st4[(long)n * 16 + (qc - 16)];
        unsigned* ap = (unsigned*)&alds[row * 136 + qc * 4];
        ap[0] = pk2(v.x, v.y);
        ap[1] = pk2(v.z, v.w);
        float4 wv = W4[idx];
        unsigned* wp = (unsigned*)&wlds[row * 136 + qc * 4];
        wp[0] = pk2(wv.x, wv.y);
        wp[1] = pk2(wv.z, wv.w);
    }
    __syncthreads();

    int lane = tid & 63;
    int w = tid >> 6;
    int lrow = lane & 15, lq = lane >> 4;

    f32x4 acc[4];
#pragma unroll
    for (int c = 0; c < 4; ++c) acc[c] = (f32x4){0.f, 0.f, 0.f, 0.f};

#pragma unroll
    for (int kc = 0; kc < 4; ++kc) {
        bf16x8 af = *(const bf16x8*)&alds[(w * 16 + lrow) * 136 + kc * 32 + lq * 8];
#pragma unroll
        for (int c = 0; c < 4; ++c) {
            bf16x8 bf = *(const bf16x8*)&wlds[(c * 16 + lrow) * 136 + kc * 32 + lq * 8];
            acc[c] = __builtin_amdgcn_mfma_f32_16x16x32_bf16(af, bf, acc[c], 0, 0, 0);
        }
    }
    __syncthreads();

    // stage fp32 h tile [64][68]; C layout col=lane&15, row=(lane>>4)*4+reg
    float* hst = (float*)alds;
#pragma unroll
    for (int r = 0; r < 4; ++r) {
        int nl = w * 16 + lq * 4 + r;
#pragma unroll
        for (int c = 0; c < 4; ++c)
            hst[nl * 68 + c * 16 + lrow] = acc[c][r];
    }
    __syncthreads();

    // coalesced outputs: thread t = (node t>>2, head t&3)
    int node = tid >> 2, chunk = tid & 3;
    int n = nb + node;
    if (n < N_NODES) {
        const float* hp = &hst[node * 68 + chunk * 16];
        float hv[16];
        float vs = 0.f, vd = 0.f;
#pragma unroll
        for (int i = 0; i < 16; ++i) {
            hv[i] = hp[i];
            vs = fmaf(hv[i], a_src[chunk * 16 + i], vs);
            vd = fmaf(hv[i], a_dst[chunk * 16 + i], vd);
        }
        unsigned pk[8];
#pragma unroll
        for (int j = 0; j < 8; ++j) pk[j] = pk2(hv[2 * j], hv[2 * j + 1]);
        uint4* dst = (uint4*)(hf2 + (long)n * 64 + chunk * 16);
        dst[0] = make_uint4(pk[0], pk[1], pk[2], pk[3]);
        dst[1] = make_uint4(pk[4], pk[5], pk[6], pk[7]);
        s_src4[(long)nb * 4 + tid] = vs;
        s_dst4[(long)nb * 4 + tid] = vd;
    }
}

// ---------------- k_agg: bucket-resident LDS accumulation (no CSR) --------------
// block = bucket of 256 dst nodes; acc[256][64] f32 + den[256][4] in LDS (68KB).
// wave = 1 edge: broadcast record + 16B score gathers (L2) + coalesced 128B h row;
// LDS atomicAdd bank = lane&31 -> conflict-free. No max pass (logits bounded,
// softmax shift-invariant). Epilogue writes out fully coalesced.
__global__ void __launch_bounds__(512, 2)
k_agg(const int* __restrict__ recs, const int* __restrict__ gcnt,
      const int* __restrict__ goff, const float* __restrict__ s_src4,
      const float* __restrict__ s_dst4, const unsigned short* __restrict__ h2,
      float* __restrict__ out) {
    __shared__ float acc[256 * 64];
    __shared__ float den[256 * 4];
    int tid = threadIdx.x;
    int b = blockIdx.x;
    for (int i = tid; i < 256 * 64; i += 512) acc[i] = 0.f;
    for (int i = tid; i < 256 * 4; i += 512) den[i] = 0.f;
    __syncthreads();

    int cntb = gcnt[b], base = goff[b];
    int lane = tid & 63, w = tid >> 6;         // 8 waves, 1 edge each per step
    int hh = lane >> 4;
    for (int i = w; i < cntb; i += 8) {
        int rec = recs[base + i];              // wave-uniform -> broadcast
        int src = rec & 0xFFFF;
        int dstl = (rec >> 16) & 0xFF;
        float ssrc = s_src4[src * 4 + hh];                 // 16B broadcast (L2)
        float sdst = s_dst4[(b * 256 + dstl) * 4 + hh];    // 16B broadcast (L2)
        float ex = __expf(leaky(ssrc + sdst));
        float hv = blo((unsigned)h2[(long)src * 64 + lane]);  // coalesced 128B
        atomicAdd(&acc[dstl * 64 + lane], ex * hv);
        if ((lane & 15) == 0) atomicAdd(&den[dstl * 4 + hh], ex);
    }
    __syncthreads();

    // epilogue: normalize + residual + ELU, coalesced float4
    for (int i = tid; i < 4096; i += 512) {
        int node = i >> 4;
        int dq = (i & 15) * 4;                 // dim quad; head = dq>>4
        int n = b * 256 + node;
        if (n >= N_NODES) continue;
        float inv = 1.0f / (den[node * 4 + (dq >> 4)] + 1e-12f);
        uint2 hr = *(const uint2*)&h2[(long)n * 64 + dq];
        float4 o;
        o.x = acc[node * 64 + dq + 0] * inv + blo(hr.x);
        o.y = acc[node * 64 + dq + 1] * inv + bhi(hr.x);
        o.z = acc[node * 64 + dq + 2] * inv + blo(hr.y);
        o.w = acc[node * 64 + dq + 3] * inv + bhi(hr.y);
        o.x = (o.x > 0.f) ? o.x : expm1f(o.x);
        o.y = (o.y > 0.f) ? o.y : expm1f(o.y);
        o.z = (o.z > 0.f) ? o.z : expm1f(o.z);
        o.w = (o.w > 0.f) ? o.w : expm1f(o.w);
        *(float4*)&out[(long)n * 64 + dq] = o;
    }
}

extern "C" void kernel_launch(void* const* d_in, const int* in_sizes, int n_in,
                              void* d_out, int out_size, void* d_ws, size_t ws_size,
                              hipStream_t stream) {
    const float* x      = (const float*)d_in[0];
    const float* state  = (const float*)d_in[1];
    const int*   ei     = (const int*)d_in[2];     // [2, E]
    // d_in[3] = edge_weight (ignored)
    const float* W      = (const float*)d_in[4];   // [64,128]
    const float* a_src  = (const float*)d_in[5];
    const float* a_dst  = (const float*)d_in[6];

    float* out = (float*)d_out;

    // ws layout: hf2 [N*64] u16 | s_src4 [N*4] f32 | s_dst4 [N*4] |
    //            gcnt[256] | goff[256] | gcur[256] | recs [E] i32
    unsigned short* hf2 = (unsigned short*)d_ws;
    float* s_src4 = (float*)(hf2 + (long)N_NODES * 64);
    float* s_dst4 = s_src4 + (long)N_NODES * 4;
    int*   gcnt   = (int*)(s_dst4 + (long)N_NODES * 4);
    int*   goff   = gcnt + 256;
    int*   gcur   = goff + 256;
    int*   recs   = gcur + 256;

    hipMemsetAsync(gcnt, 0, NBK * sizeof(int), stream);
    k_hist196<<<196, 256, 0, stream>>>(ei, gcnt);
    k_scan196<<<1, 256, 0, stream>>>(gcnt, goff, gcur);
    k_bin<<<196, 256, 0, stream>>>(ei, goff, gcur, recs);
    k1_mfma<<<782, 256, 0, stream>>>(x, state, W, a_src, a_dst,
                                     hf2, s_src4, s_dst4);
    k_agg<<<NBK, 512, 0, stream>>>(recs, gcnt, goff, s_src4, s_dst4, hf2, out);
}

// Round 12
// 81.610 us; speedup vs baseline: 5.2263x; 5.2263x over previous
//
#include <hip/hip_runtime.h>
#include <hip/hip_bf16.h>

#define N_NODES 50000
#define N_EDGES 800000
#define NBK 196          // coarse buckets of 256 dst nodes (dst>>8); 196*256 = 50176
#define BCAP 40          // per-bucket LDS stage capacity in k_bin (lambda=21, +4sigma)

typedef __attribute__((ext_vector_type(8))) short bf16x8;   // MFMA A/B frag
typedef __attribute__((ext_vector_type(4))) float f32x4;    // MFMA C/D frag

__device__ __forceinline__ float leaky(float l) { return (l >= 0.0f) ? l : 0.2f * l; }
__device__ __forceinline__ float blo(unsigned u) { return __uint_as_float(u << 16); }
__device__ __forceinline__ float bhi(unsigned u) { return __uint_as_float(u & 0xffff0000u); }
__device__ __forceinline__ unsigned short f2bu(float f) {
    __hip_bfloat16 hb = __float2bfloat16(f);   // RNE
    return *(unsigned short*)&hb;
}
__device__ __forceinline__ unsigned pk2(float a, float b) {
    return (unsigned)f2bu(a) | ((unsigned)f2bu(b) << 16);
}

// ---------------- k_hist196: per-bucket edge counts (LDS pre-aggregated) --------
__global__ void k_hist196(const int* __restrict__ ei, int* __restrict__ gcnt) {
    __shared__ int cnt[NBK];
    int tid = threadIdx.x;
    for (int i = tid; i < NBK; i += 256) cnt[i] = 0;
    __syncthreads();
    int e0 = blockIdx.x * 4096;
#pragma unroll
    for (int k = 0; k < 4; ++k) {
        int e = e0 + k * 1024 + tid * 4;
        if (e < N_EDGES) {
            int4 dv = *(const int4*)(ei + N_EDGES + e);
            atomicAdd(&cnt[dv.x >> 8], 1);
            atomicAdd(&cnt[dv.y >> 8], 1);
            atomicAdd(&cnt[dv.z >> 8], 1);
            atomicAdd(&cnt[dv.w >> 8], 1);
        }
    }
    __syncthreads();
    for (int b = tid; b < NBK; b += 256)
        if (cnt[b]) atomicAdd(&gcnt[b], cnt[b]);
}

// ---------------- k_scan196: 1-block exclusive scan -> bucket offsets -----------
__global__ void k_scan196(const int* __restrict__ gcnt, int* __restrict__ goff,
                          int* __restrict__ gcur) {
    __shared__ int wsum[4];
    int tid = threadIdx.x, lane = tid & 63, wid = tid >> 6;
    int v = (tid < NBK) ? gcnt[tid] : 0;
    int inc = v;
#pragma unroll
    for (int s = 1; s < 64; s <<= 1) {
        int t = __shfl_up(inc, s);
        if (lane >= s) inc += t;
    }
    if (lane == 63) wsum[wid] = inc;
    __syncthreads();
    if (tid == 0) {
        int s = 0;
#pragma unroll
        for (int w = 0; w < 4; ++w) { int t = wsum[w]; wsum[w] = s; s += t; }
    }
    __syncthreads();
    if (tid < NBK) {
        goff[tid] = wsum[wid] + inc - v;
        gcur[tid] = 0;
    }
}

// ---------------- k_bin: LDS-staged coarse routing (dense writes) ---------------
// Record = src | (dst&255)<<16 (src < 2^16). Bucket-internal order irrelevant.
__global__ void __launch_bounds__(256)
k_bin(const int* __restrict__ ei, const int* __restrict__ goff,
      int* __restrict__ gcur, int* __restrict__ recs) {
    __shared__ int cnt[NBK];
    __shared__ int stage[NBK][BCAP];
    int tid = threadIdx.x;
    for (int i = tid; i < NBK; i += 256) cnt[i] = 0;
    __syncthreads();
    int e0 = blockIdx.x * 4096;
#pragma unroll
    for (int k = 0; k < 4; ++k) {
        int e = e0 + k * 1024 + tid * 4;
        if (e < N_EDGES) {
            int4 sv = *(const int4*)(ei + e);
            int4 dv = *(const int4*)(ei + N_EDGES + e);
            int ss[4] = {sv.x, sv.y, sv.z, sv.w};
            int dd[4] = {dv.x, dv.y, dv.z, dv.w};
#pragma unroll
            for (int j = 0; j < 4; ++j) {
                int b = dd[j] >> 8;
                int rec = ss[j] | ((dd[j] & 255) << 16);
                int p = atomicAdd(&cnt[b], 1);
                if (p < BCAP) stage[b][p] = rec;
                else {                         // rare overflow: direct store
                    int g = atomicAdd(&gcur[b], 1);
                    recs[goff[b] + g] = rec;
                }
            }
        }
    }
    __syncthreads();
    for (int b = tid; b < NBK; b += 256) {
        int nb = min(cnt[b], BCAP);
        if (nb > 0) {
            int g = atomicAdd(&gcur[b], nb);
            int d0 = goff[b] + g;
            for (int i = 0; i < nb; ++i) recs[d0 + i] = stage[b][i];
        }
    }
}

// ---------------- k_sort: within-bucket counting sort -> dst-sorted CSR ---------
// block = bucket. Scatter stays inside the bucket's contiguous ~16KB region ->
// one XCD's L2, lines fully populated before eviction (no 64B amplification).
// Emits off[n]/deg[n] for free (replaces k_hist/k_assign).
__global__ void __launch_bounds__(256)
k_sort(const int* __restrict__ recs, const int* __restrict__ gcnt,
       const int* __restrict__ goff, int* __restrict__ recs2,
       int* __restrict__ off, int* __restrict__ deg) {
    __shared__ int cnt[256];
    __shared__ int pos[256];
    __shared__ int wsum[4];
    int tid = threadIdx.x, b = blockIdx.x;
    cnt[tid] = 0;
    __syncthreads();
    int base = goff[b], cntb = gcnt[b];
    for (int i = tid; i < cntb; i += 256)
        atomicAdd(&cnt[(recs[base + i] >> 16) & 255], 1);
    __syncthreads();
    int lane = tid & 63, wid = tid >> 6;
    int v = cnt[tid], inc = v;
#pragma unroll
    for (int s = 1; s < 64; s <<= 1) {
        int t = __shfl_up(inc, s);
        if (lane >= s) inc += t;
    }
    if (lane == 63) wsum[wid] = inc;
    __syncthreads();
    if (tid == 0) {
        int s = 0;
#pragma unroll
        for (int w = 0; w < 4; ++w) { int t = wsum[w]; wsum[w] = s; s += t; }
    }
    __syncthreads();
    int excl = wsum[wid] + inc - v;
    pos[tid] = excl;
    int n = b * 256 + tid;
    if (n < N_NODES) { off[n] = base + excl; deg[n] = v; }
    __syncthreads();
    for (int i = tid; i < cntb; i += 256) {
        int r = recs[base + i];
        int p = atomicAdd(&pos[(r >> 16) & 255], 1);
        recs2[base + p] = r & 0xFFFF;          // store src only
    }
}

// ---------------- k1: MFMA GEMM + fp32 scores, ALL outputs coalesced (R10) ------
__global__ void __launch_bounds__(256, 4)
k1_mfma(const float* __restrict__ x, const float* __restrict__ state,
        const float* __restrict__ W, const float* __restrict__ a_src,
        const float* __restrict__ a_dst,
        unsigned short* __restrict__ hf2, float* __restrict__ s_src4,
        float* __restrict__ s_dst4) {
    __shared__ unsigned short alds[64 * 136];  // A tile bf16; reused as f32 h [64][68]
    __shared__ unsigned short wlds[64 * 136];  // W tile bf16
    int tid = threadIdx.x;
    int nb = blockIdx.x * 64;

    const float4* x4  = (const float4*)x;
    const float4* st4 = (const float4*)state;
    const float4* W4  = (const float4*)W;
    for (int idx = tid; idx < 2048; idx += 256) {
        int row = idx >> 5, qc = idx & 31;
        int n = nb + row;
        float4 v = make_float4(0.f, 0.f, 0.f, 0.f);
        if (n < N_NODES)
            v = (qc < 16) ? x4[(long)n * 16 + qc] : st4[(long)n * 16 + (qc - 16)];
        unsigned* ap = (unsigned*)&alds[row * 136 + qc * 4];
        ap[0] = pk2(v.x, v.y);
        ap[1] = pk2(v.z, v.w);
        float4 wv = W4[idx];
        unsigned* wp = (unsigned*)&wlds[row * 136 + qc * 4];
        wp[0] = pk2(wv.x, wv.y);
        wp[1] = pk2(wv.z, wv.w);
    }
    __syncthreads();

    int lane = tid & 63;
    int w = tid >> 6;
    int lrow = lane & 15, lq = lane >> 4;

    f32x4 acc[4];
#pragma unroll
    for (int c = 0; c < 4; ++c) acc[c] = (f32x4){0.f, 0.f, 0.f, 0.f};

#pragma unroll
    for (int kc = 0; kc < 4; ++kc) {
        bf16x8 af = *(const bf16x8*)&alds[(w * 16 + lrow) * 136 + kc * 32 + lq * 8];
#pragma unroll
        for (int c = 0; c < 4; ++c) {
            bf16x8 bf = *(const bf16x8*)&wlds[(c * 16 + lrow) * 136 + kc * 32 + lq * 8];
            acc[c] = __builtin_amdgcn_mfma_f32_16x16x32_bf16(af, bf, acc[c], 0, 0, 0);
        }
    }
    __syncthreads();

    // stage fp32 h tile [64][68]; C layout col=lane&15, row=(lane>>4)*4+reg
    float* hst = (float*)alds;
#pragma unroll
    for (int r = 0; r < 4; ++r) {
        int nl = w * 16 + lq * 4 + r;
#pragma unroll
        for (int c = 0; c < 4; ++c)
            hst[nl * 68 + c * 16 + lrow] = acc[c][r];
    }
    __syncthreads();

    // coalesced outputs: thread t = (node t>>2, head t&3)
    int node = tid >> 2, chunk = tid & 3;
    int n = nb + node;
    if (n < N_NODES) {
        const float* hp = &hst[node * 68 + chunk * 16];
        float hv[16];
        float vs = 0.f, vd = 0.f;
#pragma unroll
        for (int i = 0; i < 16; ++i) {
            hv[i] = hp[i];
            vs = fmaf(hv[i], a_src[chunk * 16 + i], vs);
            vd = fmaf(hv[i], a_dst[chunk * 16 + i], vd);
        }
        unsigned pk[8];
#pragma unroll
        for (int j = 0; j < 8; ++j) pk[j] = pk2(hv[2 * j], hv[2 * j + 1]);
        uint4* dst = (uint4*)(hf2 + (long)n * 64 + chunk * 16);
        dst[0] = make_uint4(pk[0], pk[1], pk[2], pk[3]);
        dst[1] = make_uint4(pk[4], pk[5], pk[6], pk[7]);
        s_src4[(long)nb * 4 + tid] = vs;
        s_dst4[(long)nb * 4 + tid] = vd;
    }
}

// ---------------- k_agg: per-dst softmax + aggregation (R10 proven version) -----
// 1 wave/node, 8 edge slots in flight; NO max pass (logits bounded, softmax
// shift-invariant). csr entries are src ids (already masked in k_sort).
__global__ void k_agg(const int* __restrict__ off, const int* __restrict__ deg,
                      const int* __restrict__ csr, const float* __restrict__ s_src4,
                      const float* __restrict__ s_dst4,
                      const unsigned short* __restrict__ h2, float* __restrict__ out) {
    int wave = threadIdx.x >> 6, lane = threadIdx.x & 63;
    int n = blockIdx.x * 4 + wave;
    if (n >= N_NODES) return;
    int q = lane >> 3, d = lane & 7, hh = d >> 1;   // slot q, dim-octet d, head hh
    int b = off[n], nE = deg[n];
    float sdh = s_dst4[(long)n * 4 + hh];

    float den = 0.0f;
    float a0 = 0, a1 = 0, a2 = 0, a3 = 0, a4 = 0, a5 = 0, a6 = 0, a7 = 0;
    for (int c = 0; c < nE; c += 64) {
        int jn = min(64, nE - c);
        int svl = (lane < jn) ? csr[b + c + lane] : 0;
        for (int j = 0; j < jn; j += 8) {
            int myj = j + q;
            int s = __shfl(svl, myj);  // uniform shfl (outside divergence)
            if (myj < jn) {
                float ss = s_src4[(long)s * 4 + hh];
                float ex = __expf(leaky(ss + sdh));
                if (!(d & 1)) den += ex;           // count each (edge,head) once
                uint4 hv = *(const uint4*)(h2 + (long)s * 64 + 8 * d);
                a0 = fmaf(ex, blo(hv.x), a0);
                a1 = fmaf(ex, bhi(hv.x), a1);
                a2 = fmaf(ex, blo(hv.y), a2);
                a3 = fmaf(ex, bhi(hv.y), a3);
                a4 = fmaf(ex, blo(hv.z), a4);
                a5 = fmaf(ex, bhi(hv.z), a5);
                a6 = fmaf(ex, blo(hv.w), a6);
                a7 = fmaf(ex, bhi(hv.w), a7);
            }
        }
    }
#pragma unroll
    for (int o2 = 8; o2 < 64; o2 <<= 1) {          // reduce across the 8 slots
        den += __shfl_xor(den, o2);
        a0 += __shfl_xor(a0, o2);
        a1 += __shfl_xor(a1, o2);
        a2 += __shfl_xor(a2, o2);
        a3 += __shfl_xor(a3, o2);
        a4 += __shfl_xor(a4, o2);
        a5 += __shfl_xor(a5, o2);
        a6 += __shfl_xor(a6, o2);
        a7 += __shfl_xor(a7, o2);
    }
    den += __shfl_xor(den, 1);                     // share even-lane den to odd

    if (q == 0) {
        uint4 hr = *(const uint4*)(h2 + (long)n * 64 + 8 * d);
        float inv = 1.0f / (den + 1e-12f);
        float o[8];
        o[0] = a0 * inv + blo(hr.x);
        o[1] = a1 * inv + bhi(hr.x);
        o[2] = a2 * inv + blo(hr.y);
        o[3] = a3 * inv + bhi(hr.y);
        o[4] = a4 * inv + blo(hr.z);
        o[5] = a5 * inv + bhi(hr.z);
        o[6] = a6 * inv + blo(hr.w);
        o[7] = a7 * inv + bhi(hr.w);
#pragma unroll
        for (int k = 0; k < 8; ++k) o[k] = (o[k] > 0.0f) ? o[k] : expm1f(o[k]);
        float4 w0 = {o[0], o[1], o[2], o[3]};
        float4 w1 = {o[4], o[5], o[6], o[7]};
        *(float4*)&out[(long)n * 64 + 8 * d]     = w0;
        *(float4*)&out[(long)n * 64 + 8 * d + 4] = w1;
    }
}

extern "C" void kernel_launch(void* const* d_in, const int* in_sizes, int n_in,
                              void* d_out, int out_size, void* d_ws, size_t ws_size,
                              hipStream_t stream) {
    const float* x      = (const float*)d_in[0];
    const float* state  = (const float*)d_in[1];
    const int*   ei     = (const int*)d_in[2];     // [2, E]
    // d_in[3] = edge_weight (ignored)
    const float* W      = (const float*)d_in[4];   // [64,128]
    const float* a_src  = (const float*)d_in[5];
    const float* a_dst  = (const float*)d_in[6];

    float* out = (float*)d_out;

    // ws layout: hf2 [N*64] u16 | s_src4 [N*4] f32 | s_dst4 [N*4] |
    //            gcnt[256] | goff[256] | gcur[256] | off[N] | deg[N] |
    //            recs [E] | recs2 [E]
    unsigned short* hf2 = (unsigned short*)d_ws;
    float* s_src4 = (float*)(hf2 + (long)N_NODES * 64);
    float* s_dst4 = s_src4 + (long)N_NODES * 4;
    int*   gcnt   = (int*)(s_dst4 + (long)N_NODES * 4);
    int*   goff   = gcnt + 256;
    int*   gcur   = goff + 256;
    int*   off    = gcur + 256;
    int*   deg    = off + N_NODES;
    int*   recs   = deg + N_NODES;
    int*   recs2  = recs + N_EDGES;

    hipMemsetAsync(gcnt, 0, NBK * sizeof(int), stream);
    k_hist196<<<196, 256, 0, stream>>>(ei, gcnt);
    k_scan196<<<1, 256, 0, stream>>>(gcnt, goff, gcur);
    k_bin<<<196, 256, 0, stream>>>(ei, goff, gcur, recs);
    k_sort<<<NBK, 256, 0, stream>>>(recs, gcnt, goff, recs2, off, deg);
    k1_mfma<<<782, 256, 0, stream>>>(x, state, W, a_src, a_dst,
                                     hf2, s_src4, s_dst4);
    k_agg<<<(N_NODES + 3) / 4, 256, 0, stream>>>(off, deg, recs2, s_src4, s_dst4, hf2, out);
}